// Round 3
// baseline (3700.050 us; speedup 1.0000x reference)
//
#include <hip/hip_runtime.h>
#include <hip/hip_bf16.h>
#include <cstdint>
#include <cstddef>

// Problem constants: N=32768, D=2048, H=4096, E=8, T = N/E = 4096.
#define NTOK 32768
#define DDIM 2048
#define HDIM 4096
#define NEXP 8
#define TTOK 4096

typedef __attribute__((ext_vector_type(8))) __bf16 bf16x8;
typedef __attribute__((ext_vector_type(16))) float f32x16;

#define MFMA32(a, b, c) __builtin_amdgcn_mfma_f32_32x32x16_bf16((a), (b), (c), 0, 0, 0)

__device__ __forceinline__ unsigned short f2bf(float f) {
  unsigned int u = __builtin_bit_cast(unsigned int, f);
  u += 0x7FFFu + ((u >> 16) & 1u);   // round-to-nearest-even
  return (unsigned short)(u >> 16);
}

// ---------------- f32 -> bf16 convert (vectorized, grid-stride) ----------------
__global__ __launch_bounds__(256) void cvt_kernel(const float* __restrict__ src,
                                                  unsigned short* __restrict__ dst,
                                                  long n4) {
  long i = (long)blockIdx.x * blockDim.x + threadIdx.x;
  long stride = (long)gridDim.x * blockDim.x;
  const float4* s4 = (const float4*)src;
  ushort4* d4 = (ushort4*)dst;
  for (; i < n4; i += stride) {
    float4 v = s4[i];
    ushort4 o;
    o.x = f2bf(v.x); o.y = f2bf(v.y); o.z = f2bf(v.z); o.w = f2bf(v.w);
    d4[i] = o;
  }
}

// ------------- transpose w_down (E,H,D) f32 -> (E,D,H) bf16 -------------
__global__ __launch_bounds__(256) void transpose_wd(const float* __restrict__ w,
                                                    unsigned short* __restrict__ wt) {
  __shared__ unsigned short tile[64][66];
  const int e = blockIdx.z;
  const int h0 = blockIdx.y * 64;
  const int d0 = blockIdx.x * 64;
  const float* we = w + (size_t)e * HDIM * DDIM;
  unsigned short* wte = wt + (size_t)e * DDIM * HDIM;
  const int t = threadIdx.x;
  const int r = t >> 4;
  const int c4 = (t & 15) * 4;
#pragma unroll
  for (int p = 0; p < 4; ++p) {
    int h = r + p * 16;
    float4 v = *(const float4*)(we + (size_t)(h0 + h) * DDIM + d0 + c4);
    tile[h][c4 + 0] = f2bf(v.x);
    tile[h][c4 + 1] = f2bf(v.y);
    tile[h][c4 + 2] = f2bf(v.z);
    tile[h][c4 + 3] = f2bf(v.w);
  }
  __syncthreads();
#pragma unroll
  for (int p = 0; p < 4; ++p) {
    int d = r + p * 16;
    ushort4 o;
    o.x = tile[c4 + 0][d];
    o.y = tile[c4 + 1][d];
    o.z = tile[c4 + 2][d];
    o.w = tile[c4 + 3][d];
    *(ushort4*)(wte + (size_t)(d0 + d) * HDIM + h0 + c4) = o;
  }
}

// ------------- GEMM staging: 128 rows x 64 bf16, global_load_lds width=16 -------------
// LDS dest is linear (wave-uniform base + lane*16). Swizzle via inverse-XOR on the
// GLOBAL source granule (rule #21): LDS granule (r,c) <- global granule (r, c^(r&7)).
// Proven 0 bank conflicts (rounds 1-2).
__device__ __forceinline__ void stage128x64(const unsigned short* __restrict__ g0,
                                            size_t stride_elems,
                                            unsigned short* lds, int tid) {
#pragma unroll
  for (int i = 0; i < 4; ++i) {
    int gi = i * 256 + tid;          // granule index 0..1023 (16B granules)
    int r = gi >> 3;                 // row 0..127
    int c = gi & 7;                  // granule-in-row 0..7
    const unsigned short* src = g0 + (size_t)r * stride_elems + ((c ^ (r & 7)) << 3);
    __builtin_amdgcn_global_load_lds(
        (const __attribute__((address_space(1))) unsigned int*)src,
        (__attribute__((address_space(3))) unsigned int*)(lds + (size_t)gi * 8),
        16, 0, 0);
  }
}

__device__ __forceinline__ bf16x8 read_frag(const unsigned short* lds, int row, int cg) {
  return *(const bf16x8*)(lds + row * 64 + ((cg ^ (row & 7)) << 3));
}

// ------------- GEMM1 + SwiGLU: 128-tok x 128-h fused tile, 32x32x16 MFMA -------------
// A: 128x64 (x). B: 256x64 = [up 128 rows ; gate 128 rows]. 4 waves (2Mx2N),
// wave owns 64 tok x 64 h for BOTH up and gate. 48 KiB LDS -> 3 blocks/CU.
__global__ __launch_bounds__(256, 3) void gemm1_swiglu(
    const unsigned short* __restrict__ Xb,
    const unsigned short* __restrict__ Wb,
    unsigned short* __restrict__ Hid) {
  __shared__ unsigned short sA[128 * 64];   // 16 KiB
  __shared__ unsigned short sB[256 * 64];   // 32 KiB (up ; gate)
  const int e = blockIdx.z;
  const int bm = blockIdx.y;   // token tile (128)
  const int bn = blockIdx.x;   // h tile (128)
  const unsigned short* Xe = Xb + ((size_t)e * TTOK + bm * 128) * DDIM;
  const unsigned short* Wu = Wb + ((size_t)e * 2 * HDIM + (size_t)bn * 128) * DDIM;
  const unsigned short* Wg = Wu + (size_t)HDIM * DDIM;
  const int tid = threadIdx.x;
  const int lane = tid & 63;
  const int wid = tid >> 6;
  const int wr = (wid & 1) * 64;    // wave tok base
  const int wc = (wid >> 1) * 64;   // wave h base
  const int lrow = lane & 31;
  const int lhi = lane >> 5;        // k-half within 16-K slice

  f32x16 au[2][2], ag[2][2];
#pragma unroll
  for (int i = 0; i < 2; ++i)
#pragma unroll
    for (int j = 0; j < 2; ++j) {
      au[i][j] = (f32x16)(0.f);
      ag[i][j] = (f32x16)(0.f);
    }

  for (int kt = 0; kt < DDIM / 64; ++kt) {
    if (kt) __syncthreads();
    stage128x64(Xe + kt * 64, DDIM, sA, tid);
    stage128x64(Wu + kt * 64, DDIM, sB, tid);
    stage128x64(Wg + kt * 64, DDIM, sB + 128 * 64, tid);
    __syncthreads();
#pragma unroll
    for (int ks = 0; ks < 4; ++ks) {        // four K=16 slices of BK=64
      const int cg = ks * 2 + lhi;          // 16B granule index in the 64-col row
      bf16x8 a0 = read_frag(sA, wr + lrow, cg);
      bf16x8 a1 = read_frag(sA, wr + 32 + lrow, cg);
      bf16x8 u0 = read_frag(sB, wc + lrow, cg);
      bf16x8 u1 = read_frag(sB, wc + 32 + lrow, cg);
      bf16x8 g0 = read_frag(sB, 128 + wc + lrow, cg);
      bf16x8 g1 = read_frag(sB, 128 + wc + 32 + lrow, cg);
      au[0][0] = MFMA32(a0, u0, au[0][0]);
      au[0][1] = MFMA32(a0, u1, au[0][1]);
      au[1][0] = MFMA32(a1, u0, au[1][0]);
      au[1][1] = MFMA32(a1, u1, au[1][1]);
      ag[0][0] = MFMA32(a0, g0, ag[0][0]);
      ag[0][1] = MFMA32(a0, g1, ag[0][1]);
      ag[1][0] = MFMA32(a1, g0, ag[1][0]);
      ag[1][1] = MFMA32(a1, g1, ag[1][1]);
    }
  }

  // epilogue: hidden = up * silu(gate)
  // C/D layout (m74/m101): col = lane&31, row = (reg&3) + 8*(reg>>2) + 4*(lane>>5)
  unsigned short* He = Hid + ((size_t)e * TTOK + bm * 128) * HDIM + (size_t)bn * 128;
#pragma unroll
  for (int mi = 0; mi < 2; ++mi)
#pragma unroll
    for (int ni = 0; ni < 2; ++ni)
#pragma unroll
      for (int r = 0; r < 16; ++r) {
        int row = wr + mi * 32 + (r & 3) + 8 * (r >> 2) + 4 * lhi;
        int col = wc + ni * 32 + lrow;
        float u = au[mi][ni][r];
        float g = ag[mi][ni][r];
        He[(size_t)row * HDIM + col] = f2bf(u * g / (1.f + __expf(-g)));
      }
}

// ------------- GEMM2: out = hidden @ w_downT, 128-tok x 256-d tile, 32x32x16 -------------
__global__ __launch_bounds__(256, 3) void gemm2_down(
    const unsigned short* __restrict__ Hid,
    const unsigned short* __restrict__ WdT,
    float* __restrict__ Out) {
  __shared__ unsigned short sA[128 * 64];   // 16 KiB
  __shared__ unsigned short sB[256 * 64];   // 32 KiB
  const int e = blockIdx.z;
  const int bm = blockIdx.y;   // token tile (128)
  const int bn = blockIdx.x;   // d tile (256)
  const unsigned short* Ae = Hid + ((size_t)e * TTOK + bm * 128) * HDIM;
  const unsigned short* Be = WdT + ((size_t)e * DDIM + (size_t)bn * 256) * HDIM;
  const int tid = threadIdx.x;
  const int lane = tid & 63;
  const int wid = tid >> 6;
  const int wr = (wid & 1) * 64;     // wave tok base
  const int wc = (wid >> 1) * 128;   // wave d base
  const int lrow = lane & 31;
  const int lhi = lane >> 5;

  f32x16 acc[2][4];
#pragma unroll
  for (int i = 0; i < 2; ++i)
#pragma unroll
    for (int j = 0; j < 4; ++j) acc[i][j] = (f32x16)(0.f);

  for (int kt = 0; kt < HDIM / 64; ++kt) {
    if (kt) __syncthreads();
    stage128x64(Ae + kt * 64, HDIM, sA, tid);
    stage128x64(Be + kt * 64, HDIM, sB, tid);
    stage128x64(Be + (size_t)128 * HDIM + kt * 64, HDIM, sB + 128 * 64, tid);
    __syncthreads();
#pragma unroll
    for (int ks = 0; ks < 4; ++ks) {
      const int cg = ks * 2 + lhi;
      bf16x8 a0 = read_frag(sA, wr + lrow, cg);
      bf16x8 a1 = read_frag(sA, wr + 32 + lrow, cg);
      bf16x8 b0 = read_frag(sB, wc + lrow, cg);
      bf16x8 b1 = read_frag(sB, wc + 32 + lrow, cg);
      bf16x8 b2 = read_frag(sB, wc + 64 + lrow, cg);
      bf16x8 b3 = read_frag(sB, wc + 96 + lrow, cg);
      acc[0][0] = MFMA32(a0, b0, acc[0][0]);
      acc[0][1] = MFMA32(a0, b1, acc[0][1]);
      acc[0][2] = MFMA32(a0, b2, acc[0][2]);
      acc[0][3] = MFMA32(a0, b3, acc[0][3]);
      acc[1][0] = MFMA32(a1, b0, acc[1][0]);
      acc[1][1] = MFMA32(a1, b1, acc[1][1]);
      acc[1][2] = MFMA32(a1, b2, acc[1][2]);
      acc[1][3] = MFMA32(a1, b3, acc[1][3]);
    }
  }

  float* Oe = Out + ((size_t)e * TTOK + bm * 128) * DDIM + (size_t)bn * 256;
#pragma unroll
  for (int mi = 0; mi < 2; ++mi)
#pragma unroll
    for (int ni = 0; ni < 4; ++ni)
#pragma unroll
      for (int r = 0; r < 16; ++r) {
        int row = wr + mi * 32 + (r & 3) + 8 * (r >> 2) + 4 * lhi;
        int col = wc + ni * 32 + lrow;
        Oe[(size_t)row * DDIM + col] = acc[mi][ni][r];
      }
}

extern "C" void kernel_launch(void* const* d_in, const int* in_sizes, int n_in,
                              void* d_out, int out_size, void* d_ws, size_t ws_size,
                              hipStream_t stream) {
  const float* x = (const float*)d_in[0];
  const float* wug = (const float*)d_in[1];
  const float* wd = (const float*)d_in[2];
  float* out = (float*)d_out;

  unsigned short* xb   = (unsigned short*)d_ws;                    // 32768*2048
  unsigned short* wugb = xb   + (size_t)NTOK * DDIM;               // 8*8192*2048
  unsigned short* wdT  = wugb + (size_t)NEXP * 2 * HDIM * DDIM;    // 8*2048*4096
  unsigned short* hid  = wdT  + (size_t)NEXP * DDIM * HDIM;        // 8*4096*4096

  cvt_kernel<<<4096, 256, 0, stream>>>(x, xb, (long)NTOK * DDIM / 4);
  cvt_kernel<<<4096, 256, 0, stream>>>(wug, wugb, (long)NEXP * 2 * HDIM * DDIM / 4);
  transpose_wd<<<dim3(DDIM / 64, HDIM / 64, NEXP), 256, 0, stream>>>(wd, wdT);
  gemm1_swiglu<<<dim3(HDIM / 128, TTOK / 128, NEXP), 256, 0, stream>>>(xb, wugb, hid);
  gemm2_down<<<dim3(DDIM / 256, TTOK / 128, NEXP), 256, 0, stream>>>(hid, wdT, out);
}

// Round 4
// 2190.640 us; speedup vs baseline: 1.6890x; 1.6890x over previous
//
#include <hip/hip_runtime.h>
#include <hip/hip_bf16.h>
#include <cstdint>
#include <cstddef>

// Problem constants: N=32768, D=2048, H=4096, E=8, T = N/E = 4096.
#define NTOK 32768
#define DDIM 2048
#define HDIM 4096
#define NEXP 8
#define TTOK 4096

typedef __attribute__((ext_vector_type(8))) __bf16 bf16x8;
typedef __attribute__((ext_vector_type(4))) float f32x4;

#define MFMA_BF16(a, b, c) __builtin_amdgcn_mfma_f32_16x16x32_bf16((a), (b), (c), 0, 0, 0)
#define SBAR() __builtin_amdgcn_s_barrier()
#define SCHED0() __builtin_amdgcn_sched_barrier(0)
#define WAIT_VM(n) asm volatile("s_waitcnt vmcnt(" #n ")" ::: "memory")
#define WAIT_LGKM0() asm volatile("s_waitcnt lgkmcnt(0)" ::: "memory")

__device__ __forceinline__ unsigned short f2bf(float f) {
  unsigned int u = __builtin_bit_cast(unsigned int, f);
  u += 0x7FFFu + ((u >> 16) & 1u);   // round-to-nearest-even
  return (unsigned short)(u >> 16);
}

// ---------------- f32 -> bf16 convert (vectorized, grid-stride) ----------------
__global__ __launch_bounds__(256) void cvt_kernel(const float* __restrict__ src,
                                                  unsigned short* __restrict__ dst,
                                                  long n4) {
  long i = (long)blockIdx.x * blockDim.x + threadIdx.x;
  long stride = (long)gridDim.x * blockDim.x;
  const float4* s4 = (const float4*)src;
  ushort4* d4 = (ushort4*)dst;
  for (; i < n4; i += stride) {
    float4 v = s4[i];
    ushort4 o;
    o.x = f2bf(v.x); o.y = f2bf(v.y); o.z = f2bf(v.z); o.w = f2bf(v.w);
    d4[i] = o;
  }
}

// ------------- transpose w_down (E,H,D) f32 -> (E,D,H) bf16 -------------
__global__ __launch_bounds__(256) void transpose_wd(const float* __restrict__ w,
                                                    unsigned short* __restrict__ wt) {
  __shared__ unsigned short tile[64][66];
  const int e = blockIdx.z;
  const int h0 = blockIdx.y * 64;
  const int d0 = blockIdx.x * 64;
  const float* we = w + (size_t)e * HDIM * DDIM;
  unsigned short* wte = wt + (size_t)e * DDIM * HDIM;
  const int t = threadIdx.x;
  const int r = t >> 4;
  const int c4 = (t & 15) * 4;
#pragma unroll
  for (int p = 0; p < 4; ++p) {
    int h = r + p * 16;
    float4 v = *(const float4*)(we + (size_t)(h0 + h) * DDIM + d0 + c4);
    tile[h][c4 + 0] = f2bf(v.x);
    tile[h][c4 + 1] = f2bf(v.y);
    tile[h][c4 + 2] = f2bf(v.z);
    tile[h][c4 + 3] = f2bf(v.w);
  }
  __syncthreads();
#pragma unroll
  for (int p = 0; p < 4; ++p) {
    int d = r + p * 16;
    ushort4 o;
    o.x = tile[c4 + 0][d];
    o.y = tile[c4 + 1][d];
    o.z = tile[c4 + 2][d];
    o.w = tile[c4 + 3][d];
    *(ushort4*)(wte + (size_t)(d0 + d) * HDIM + h0 + c4) = o;
  }
}

// ------------- GEMM staging: 128 rows x 64 bf16, global_load_lds width=16 -------------
// LDS dest linear; swizzle via inverse-XOR on the GLOBAL source granule (rule #21).
// 4 global_load_lds per thread per call (256 threads). Proven 0 bank conflicts.
__device__ __forceinline__ void stage128x64(const unsigned short* __restrict__ g0,
                                            size_t stride_elems,
                                            unsigned short* lds, int tid) {
#pragma unroll
  for (int i = 0; i < 4; ++i) {
    int gi = i * 256 + tid;          // granule index 0..1023 (16B granules)
    int r = gi >> 3;                 // row 0..127
    int c = gi & 7;                  // granule-in-row 0..7
    const unsigned short* src = g0 + (size_t)r * stride_elems + ((c ^ (r & 7)) << 3);
    __builtin_amdgcn_global_load_lds(
        (const __attribute__((address_space(1))) unsigned int*)src,
        (__attribute__((address_space(3))) unsigned int*)(lds + (size_t)gi * 8),
        16, 0, 0);
  }
}

__device__ __forceinline__ bf16x8 read_frag(const unsigned short* lds, int row, int cg) {
  return *(const bf16x8*)(lds + row * 64 + ((cg ^ (row & 7)) << 3));
}

// ------------- GEMM1 + SwiGLU: 128x128 tile, split-stage pipeline -------------
// A (x) single-buffered 16KB; Bu/Bg double-buffered 2x16KB each = 80KB total.
// Iter t: vmcnt(8)+bar -> compute(sA, sBu/g[t&1]) -> bar -> stage A(t+1) -> stage B(t+2).
// B gets ~2 iterations in flight; A exposed but L2-hot via XCD swizzle.
__global__ __launch_bounds__(256, 2) void gemm1_swiglu(
    const unsigned short* __restrict__ Xb,
    const unsigned short* __restrict__ Wb,
    unsigned short* __restrict__ Hid) {
  __shared__ unsigned short sA[128 * 64];        // 16 KiB
  __shared__ unsigned short sBu[2][128 * 64];    // 32 KiB
  __shared__ unsigned short sBg[2][128 * 64];    // 32 KiB
  // XCD-aware swizzle: nwg=8192 (%8==0). XCD k gets 1024 consecutive wg;
  // bn fastest -> 32 bn-blocks sharing one x-panel run on the same XCD (L2-hot A).
  const int lin = blockIdx.x;
  const int wg = ((lin & 7) << 10) | (lin >> 3);
  const int bn = wg & 31;
  const int bm = (wg >> 5) & 31;
  const int e = wg >> 10;
  const unsigned short* Xe = Xb + ((size_t)e * TTOK + bm * 128) * DDIM;
  const unsigned short* Wu = Wb + ((size_t)e * 2 * HDIM + (size_t)bn * 128) * DDIM;
  const unsigned short* Wg = Wu + (size_t)HDIM * DDIM;
  const int tid = threadIdx.x;
  const int lane = tid & 63;
  const int wid = tid >> 6;
  const int wm = (wid & 1) * 64;
  const int wn = (wid >> 1) * 64;
  const int lr = lane & 15;
  const int lk = lane >> 4;

  f32x4 au[4][4], ag[4][4];
#pragma unroll
  for (int i = 0; i < 4; ++i)
#pragma unroll
    for (int j = 0; j < 4; ++j) {
      au[i][j] = f32x4{0.f, 0.f, 0.f, 0.f};
      ag[i][j] = f32x4{0.f, 0.f, 0.f, 0.f};
    }

  const int NT = DDIM / 64;   // 32
  // Prologue issue order matters for vmcnt counting: B(0)(8), A(0)(4), B(1)(8).
  stage128x64(Wu, DDIM, sBu[0], tid);
  stage128x64(Wg, DDIM, sBg[0], tid);
  stage128x64(Xe, DDIM, sA, tid);
  stage128x64(Wu + 64, DDIM, sBu[1], tid);
  stage128x64(Wg + 64, DDIM, sBg[1], tid);

  for (int t = 0; t < NT; ++t) {
    const int cur = t & 1;
    // Wait: B(t)+A(t) landed (the 12 oldest); leave B(t+1)'s 8 in flight.
    if (t + 1 < NT) { WAIT_VM(8); } else { WAIT_VM(0); }
    SBAR();
    SCHED0();
    const unsigned short* bu = sBu[cur];
    const unsigned short* bg = sBg[cur];
#pragma unroll
    for (int kh = 0; kh < 2; ++kh) {
      const int cg = kh * 4 + lk;
      bf16x8 a[4], u[4], g[4];
#pragma unroll
      for (int mi = 0; mi < 4; ++mi) a[mi] = read_frag(sA, wm + mi * 16 + lr, cg);
#pragma unroll
      for (int ni = 0; ni < 4; ++ni) u[ni] = read_frag(bu, wn + ni * 16 + lr, cg);
#pragma unroll
      for (int ni = 0; ni < 4; ++ni) g[ni] = read_frag(bg, wn + ni * 16 + lr, cg);
#pragma unroll
      for (int mi = 0; mi < 4; ++mi)
#pragma unroll
        for (int ni = 0; ni < 4; ++ni) {
          au[mi][ni] = MFMA_BF16(a[mi], u[ni], au[mi][ni]);
          ag[mi][ni] = MFMA_BF16(a[mi], g[ni], ag[mi][ni]);
        }
    }
    SCHED0();
    WAIT_LGKM0();
    SBAR();                 // all waves done reading sA and sB*[cur]
    SCHED0();
    if (t + 1 < NT) stage128x64(Xe + (t + 1) * 64, DDIM, sA, tid);          // A(t+1): 4 loads
    if (t + 2 < NT) {
      stage128x64(Wu + (t + 2) * 64, DDIM, sBu[cur], tid);                  // B(t+2): 8 loads
      stage128x64(Wg + (t + 2) * 64, DDIM, sBg[cur], tid);
    }
  }

  unsigned short* He = Hid + ((size_t)e * TTOK + bm * 128) * HDIM + (size_t)bn * 128;
#pragma unroll
  for (int mi = 0; mi < 4; ++mi)
#pragma unroll
    for (int ni = 0; ni < 4; ++ni)
#pragma unroll
      for (int r = 0; r < 4; ++r) {
        int row = wm + mi * 16 + lk * 4 + r;
        int col = wn + ni * 16 + lr;
        float up = au[mi][ni][r];
        float gv = ag[mi][ni][r];
        He[(size_t)row * HDIM + col] = f2bf(up * gv / (1.f + __expf(-gv)));
      }
}

// ------------- GEMM2: out = hidden @ w_downT, 128x128 tile, full double-buffer -------------
__global__ __launch_bounds__(256, 2) void gemm2_down(
    const unsigned short* __restrict__ Hid,
    const unsigned short* __restrict__ WdT,
    float* __restrict__ Out) {
  __shared__ unsigned short sA[2][128 * 64];   // 32 KiB
  __shared__ unsigned short sB[2][128 * 64];   // 32 KiB
  // XCD swizzle: nwg=4096, 512 per XCD; bn fastest.
  const int lin = blockIdx.x;
  const int wg = ((lin & 7) << 9) | (lin >> 3);
  const int bn = wg & 15;
  const int bm = (wg >> 4) & 31;
  const int e = wg >> 9;
  const unsigned short* Ae = Hid + ((size_t)e * TTOK + bm * 128) * HDIM;
  const unsigned short* Be = WdT + ((size_t)e * DDIM + (size_t)bn * 128) * HDIM;
  const int tid = threadIdx.x;
  const int lane = tid & 63;
  const int wid = tid >> 6;
  const int wm = (wid & 1) * 64;
  const int wn = (wid >> 1) * 64;
  const int lr = lane & 15;
  const int lk = lane >> 4;

  f32x4 acc[4][4];
#pragma unroll
  for (int i = 0; i < 4; ++i)
#pragma unroll
    for (int j = 0; j < 4; ++j) acc[i][j] = f32x4{0.f, 0.f, 0.f, 0.f};

  const int NT = HDIM / 64;   // 64
  // Prologue: AB(0) (8 loads), AB(1) (8 loads).
  stage128x64(Ae, HDIM, sA[0], tid);
  stage128x64(Be, HDIM, sB[0], tid);
  stage128x64(Ae + 64, HDIM, sA[1], tid);
  stage128x64(Be + 64, HDIM, sB[1], tid);

  for (int t = 0; t < NT; ++t) {
    const int cur = t & 1;
    if (t + 1 < NT) { WAIT_VM(8); } else { WAIT_VM(0); }
    SBAR();
    SCHED0();
    const unsigned short* a = sA[cur];
    const unsigned short* b = sB[cur];
#pragma unroll
    for (int kh = 0; kh < 2; ++kh) {
      const int cg = kh * 4 + lk;
      bf16x8 af[4], bf[4];
#pragma unroll
      for (int mi = 0; mi < 4; ++mi) af[mi] = read_frag(a, wm + mi * 16 + lr, cg);
#pragma unroll
      for (int ni = 0; ni < 4; ++ni) bf[ni] = read_frag(b, wn + ni * 16 + lr, cg);
#pragma unroll
      for (int mi = 0; mi < 4; ++mi)
#pragma unroll
        for (int ni = 0; ni < 4; ++ni)
          acc[mi][ni] = MFMA_BF16(af[mi], bf[ni], acc[mi][ni]);
    }
    SCHED0();
    WAIT_LGKM0();
    SBAR();
    SCHED0();
    if (t + 2 < NT) {
      stage128x64(Ae + (t + 2) * 64, HDIM, sA[cur], tid);   // AB(t+2): 8 loads
      stage128x64(Be + (t + 2) * 64, HDIM, sB[cur], tid);
    }
  }

  float* Oe = Out + ((size_t)e * TTOK + bm * 128) * DDIM + (size_t)bn * 128;
#pragma unroll
  for (int mi = 0; mi < 4; ++mi)
#pragma unroll
    for (int ni = 0; ni < 4; ++ni)
#pragma unroll
      for (int r = 0; r < 4; ++r) {
        int row = wm + mi * 16 + lk * 4 + r;
        int col = wn + ni * 16 + lr;
        Oe[(size_t)row * DDIM + col] = acc[mi][ni][r];
      }
}

extern "C" void kernel_launch(void* const* d_in, const int* in_sizes, int n_in,
                              void* d_out, int out_size, void* d_ws, size_t ws_size,
                              hipStream_t stream) {
  const float* x = (const float*)d_in[0];
  const float* wug = (const float*)d_in[1];
  const float* wd = (const float*)d_in[2];
  float* out = (float*)d_out;

  unsigned short* xb   = (unsigned short*)d_ws;                    // 32768*2048
  unsigned short* wugb = xb   + (size_t)NTOK * DDIM;               // 8*8192*2048
  unsigned short* wdT  = wugb + (size_t)NEXP * 2 * HDIM * DDIM;    // 8*2048*4096
  unsigned short* hid  = wdT  + (size_t)NEXP * DDIM * HDIM;        // 8*4096*4096

  cvt_kernel<<<4096, 256, 0, stream>>>(x, xb, (long)NTOK * DDIM / 4);
  cvt_kernel<<<4096, 256, 0, stream>>>(wug, wugb, (long)NEXP * 2 * HDIM * DDIM / 4);
  transpose_wd<<<dim3(DDIM / 64, HDIM / 64, NEXP), 256, 0, stream>>>(wd, wdT);
  gemm1_swiglu<<<32 * 32 * NEXP, 256, 0, stream>>>(xb, wugb, hid);
  gemm2_down<<<16 * 32 * NEXP, 256, 0, stream>>>(hid, wdT, out);
}

// Round 5
// 1684.993 us; speedup vs baseline: 2.1959x; 1.3001x over previous
//
#include <hip/hip_runtime.h>
#include <hip/hip_bf16.h>
#include <cstdint>
#include <cstddef>

// Problem constants: N=32768, D=2048, H=4096, E=8, T = N/E = 4096.
#define NTOK 32768
#define DDIM 2048
#define HDIM 4096
#define NEXP 8
#define TTOK 4096

typedef __attribute__((ext_vector_type(8))) __bf16 bf16x8;
typedef __attribute__((ext_vector_type(4))) float f32x4;

#define MFMA_BF16(a, b, c) __builtin_amdgcn_mfma_f32_16x16x32_bf16((a), (b), (c), 0, 0, 0)
#define SBAR() __builtin_amdgcn_s_barrier()
#define SCHED0() __builtin_amdgcn_sched_barrier(0)
#define WAIT_VM8() asm volatile("s_waitcnt vmcnt(8)" ::: "memory")
#define WAIT_VM0() asm volatile("s_waitcnt vmcnt(0)" ::: "memory")

__device__ __forceinline__ unsigned short f2bf(float f) {
  unsigned int u = __builtin_bit_cast(unsigned int, f);
  u += 0x7FFFu + ((u >> 16) & 1u);   // round-to-nearest-even
  return (unsigned short)(u >> 16);
}

// ---------------- f32 -> bf16 convert (vectorized, grid-stride) ----------------
__global__ __launch_bounds__(256) void cvt_kernel(const float* __restrict__ src,
                                                  unsigned short* __restrict__ dst,
                                                  long n4) {
  long i = (long)blockIdx.x * blockDim.x + threadIdx.x;
  long stride = (long)gridDim.x * blockDim.x;
  const float4* s4 = (const float4*)src;
  ushort4* d4 = (ushort4*)dst;
  for (; i < n4; i += stride) {
    float4 v = s4[i];
    ushort4 o;
    o.x = f2bf(v.x); o.y = f2bf(v.y); o.z = f2bf(v.z); o.w = f2bf(v.w);
    d4[i] = o;
  }
}

// ------------- transpose w_down (E,H,D) f32 -> (E,D,H) bf16 -------------
__global__ __launch_bounds__(256) void transpose_wd(const float* __restrict__ w,
                                                    unsigned short* __restrict__ wt) {
  __shared__ unsigned short tile[64][66];
  const int e = blockIdx.z;
  const int h0 = blockIdx.y * 64;
  const int d0 = blockIdx.x * 64;
  const float* we = w + (size_t)e * HDIM * DDIM;
  unsigned short* wte = wt + (size_t)e * DDIM * HDIM;
  const int t = threadIdx.x;
  const int r = t >> 4;
  const int c4 = (t & 15) * 4;
#pragma unroll
  for (int p = 0; p < 4; ++p) {
    int h = r + p * 16;
    float4 v = *(const float4*)(we + (size_t)(h0 + h) * DDIM + d0 + c4);
    tile[h][c4 + 0] = f2bf(v.x);
    tile[h][c4 + 1] = f2bf(v.y);
    tile[h][c4 + 2] = f2bf(v.z);
    tile[h][c4 + 3] = f2bf(v.w);
  }
  __syncthreads();
#pragma unroll
  for (int p = 0; p < 4; ++p) {
    int d = r + p * 16;
    ushort4 o;
    o.x = tile[c4 + 0][d];
    o.y = tile[c4 + 1][d];
    o.z = tile[c4 + 2][d];
    o.w = tile[c4 + 3][d];
    *(ushort4*)(wte + (size_t)(d0 + d) * HDIM + h0 + c4) = o;
  }
}

// ------------- staging: half-tile = 128 rows x 64 bf16, 512 threads x 2 loads -------------
// LDS dest linear; swizzle via inverse-XOR on the GLOBAL source granule (rule #21).
// Proven 0 bank conflicts (rounds 1-4).
__device__ __forceinline__ void stage_half(const unsigned short* __restrict__ g0,
                                           size_t stride_elems,
                                           unsigned short* lds, int tid) {
#pragma unroll
  for (int i = 0; i < 2; ++i) {
    int gi = i * 512 + tid;          // granule 0..1023 (16B); r=row 0..127, c=granule 0..7
    int r = gi >> 3;
    int c = gi & 7;
    const unsigned short* src = g0 + (size_t)r * stride_elems + ((c ^ (r & 7)) << 3);
    __builtin_amdgcn_global_load_lds(
        (const __attribute__((address_space(1))) unsigned int*)src,
        (__attribute__((address_space(3))) unsigned int*)(lds + (size_t)gi * 8),
        16, 0, 0);
  }
}

__device__ __forceinline__ bf16x8 read_frag(const unsigned short* lds, int row, int cg) {
  return *(const bf16x8*)(lds + row * 64 + ((cg ^ (row & 7)) << 3));
}

// ------------- GEMM1 + SwiGLU: 256-tok x 128-h tile, 4-phase/K-tile counted-vmcnt -------------
// A tile 256x64 (x); B tile 256x64 = [up 128 ; gate 128]. 8 waves = 2M x 4N;
// wave owns 128 tok x 32 h for BOTH up and gate (acc 32 f32x4 = 128 VGPR).
// Phases per K-tile t: ph1 (m0,u) | ph2 (m0,g)+stage B0(t+2) | ph3 (m1,u)+stage B1 |
// ph4 (m1,g)+stage A0,A1.  vmcnt(8) once per tile (8 loads/thread/tile, 2 tiles deep).
__global__ __launch_bounds__(512, 2) void gemm1_swiglu(
    const unsigned short* __restrict__ Xb,
    const unsigned short* __restrict__ Wb,
    unsigned short* __restrict__ Hid) {
  __shared__ unsigned short smem[2][2][256 * 64];   // [buf][A=0,B=1]  128 KiB
  const int e = blockIdx.z;
  const int bm = blockIdx.y;   // token tile (256)
  const int bn = blockIdx.x;   // h tile (128)
  const unsigned short* Xe = Xb + ((size_t)e * TTOK + bm * 256) * DDIM;
  const unsigned short* Wu = Wb + ((size_t)e * 2 * HDIM + (size_t)bn * 128) * DDIM;
  const unsigned short* Wg = Wu + (size_t)HDIM * DDIM;
  const int tid = threadIdx.x;
  const int lane = tid & 63;
  const int wid = tid >> 6;
  const int wm = (wid & 1) * 128;   // M-half rows
  const int wn = (wid >> 1) * 32;   // h cols within 128
  const int lr = lane & 15;
  const int lk = lane >> 4;

  f32x4 au[8][2], ag[8][2];
#pragma unroll
  for (int i = 0; i < 8; ++i)
#pragma unroll
    for (int j = 0; j < 2; ++j) {
      au[i][j] = f32x4{0.f, 0.f, 0.f, 0.f};
      ag[i][j] = f32x4{0.f, 0.f, 0.f, 0.f};
    }

  auto stageA = [&](int t, int half) {
    stage_half(Xe + (size_t)(half * 128) * DDIM + t * 64, DDIM,
               (unsigned short*)smem[t & 1][0] + half * (128 * 64), tid);
  };
  auto stageB = [&](int t, int half) {   // half0 = up rows, half1 = gate rows
    stage_half((half ? Wg : Wu) + t * 64, DDIM,
               (unsigned short*)smem[t & 1][1] + half * (128 * 64), tid);
  };

  // prologue: tiles 0 and 1 (8 loads/thread each)
  stageB(0, 0); stageB(0, 1); stageA(0, 0); stageA(0, 1);
  stageB(1, 0); stageB(1, 1); stageA(1, 0); stageA(1, 1);

  const int NT = DDIM / 64;   // 32
  for (int t = 0; t < NT; ++t) {
    const unsigned short* A = smem[t & 1][0];
    const unsigned short* B = smem[t & 1][1];
    if (t + 1 < NT) { WAIT_VM8(); } else { WAIT_VM0(); }
    SBAR(); SCHED0();
    bf16x8 a0[4][2], a1[4][2], bu[2][2], bg[2][2];
    // ---- ph1: read a0(8), bu(4); MFMA (m0, up)
#pragma unroll
    for (int mi = 0; mi < 4; ++mi)
#pragma unroll
      for (int kh = 0; kh < 2; ++kh)
        a0[mi][kh] = read_frag(A, wm + mi * 16 + lr, kh * 4 + lk);
#pragma unroll
    for (int ni = 0; ni < 2; ++ni)
#pragma unroll
      for (int kh = 0; kh < 2; ++kh)
        bu[ni][kh] = read_frag(B, wn + ni * 16 + lr, kh * 4 + lk);
    __builtin_amdgcn_s_setprio(1);
#pragma unroll
    for (int kh = 0; kh < 2; ++kh)
#pragma unroll
      for (int mi = 0; mi < 4; ++mi)
#pragma unroll
        for (int ni = 0; ni < 2; ++ni)
          au[mi][ni] = MFMA_BF16(a0[mi][kh], bu[ni][kh], au[mi][ni]);
    __builtin_amdgcn_s_setprio(0);
    SBAR(); SCHED0();
    // ---- ph2: read bg(4); stage B0(t+2); MFMA (m0, gate)
#pragma unroll
    for (int ni = 0; ni < 2; ++ni)
#pragma unroll
      for (int kh = 0; kh < 2; ++kh)
        bg[ni][kh] = read_frag(B, 128 + wn + ni * 16 + lr, kh * 4 + lk);
    if (t + 2 < NT) stageB(t + 2, 0);
    __builtin_amdgcn_s_setprio(1);
#pragma unroll
    for (int kh = 0; kh < 2; ++kh)
#pragma unroll
      for (int mi = 0; mi < 4; ++mi)
#pragma unroll
        for (int ni = 0; ni < 2; ++ni)
          ag[mi][ni] = MFMA_BF16(a0[mi][kh], bg[ni][kh], ag[mi][ni]);
    __builtin_amdgcn_s_setprio(0);
    SBAR(); SCHED0();
    // ---- ph3: read a1(8); stage B1(t+2); MFMA (m1, up)
#pragma unroll
    for (int mi = 0; mi < 4; ++mi)
#pragma unroll
      for (int kh = 0; kh < 2; ++kh)
        a1[mi][kh] = read_frag(A, wm + 64 + mi * 16 + lr, kh * 4 + lk);
    if (t + 2 < NT) stageB(t + 2, 1);
    __builtin_amdgcn_s_setprio(1);
#pragma unroll
    for (int kh = 0; kh < 2; ++kh)
#pragma unroll
      for (int mi = 0; mi < 4; ++mi)
#pragma unroll
        for (int ni = 0; ni < 2; ++ni)
          au[4 + mi][ni] = MFMA_BF16(a1[mi][kh], bu[ni][kh], au[4 + mi][ni]);
    __builtin_amdgcn_s_setprio(0);
    SBAR(); SCHED0();
    // ---- ph4: stage A0,A1(t+2); MFMA (m1, gate)
    if (t + 2 < NT) { stageA(t + 2, 0); stageA(t + 2, 1); }
    __builtin_amdgcn_s_setprio(1);
#pragma unroll
    for (int kh = 0; kh < 2; ++kh)
#pragma unroll
      for (int mi = 0; mi < 4; ++mi)
#pragma unroll
        for (int ni = 0; ni < 2; ++ni)
          ag[4 + mi][ni] = MFMA_BF16(a1[mi][kh], bg[ni][kh], ag[4 + mi][ni]);
    __builtin_amdgcn_s_setprio(0);
    // tile-closing barrier = next iteration's top barrier
  }

  // epilogue: hidden = up * silu(gate); C layout col=lane&15, row=(lane>>4)*4+reg
  unsigned short* He = Hid + ((size_t)e * TTOK + bm * 256) * HDIM + (size_t)bn * 128;
#pragma unroll
  for (int mi = 0; mi < 8; ++mi) {
    int mrow = wm + ((mi < 4) ? mi * 16 : 64 + (mi - 4) * 16);
#pragma unroll
    for (int ni = 0; ni < 2; ++ni)
#pragma unroll
      for (int r = 0; r < 4; ++r) {
        int row = mrow + lk * 4 + r;
        int col = wn + ni * 16 + lr;
        float u = au[mi][ni][r];
        float g = ag[mi][ni][r];
        He[(size_t)row * HDIM + col] = f2bf(u * g / (1.f + __expf(-g)));
      }
  }
}

// ------------- GEMM2: out = hidden @ w_downT, 256x256 tile, 4-phase/K-tile -------------
// Phases: ph1 (m0,n0) | ph2 (m0,n1) | ph3 (m1,n0)+stage B0,B1(t+2) | ph4 (m1,n1)+stage A0,A1.
__global__ __launch_bounds__(512, 2) void gemm2_down(
    const unsigned short* __restrict__ Hid,
    const unsigned short* __restrict__ WdT,
    float* __restrict__ Out) {
  __shared__ unsigned short smem[2][2][256 * 64];   // 128 KiB
  const int e = blockIdx.z;
  const int bm = blockIdx.y;   // token tile (256)
  const int bn = blockIdx.x;   // d tile (256)
  const unsigned short* Ae = Hid + ((size_t)e * TTOK + bm * 256) * HDIM;
  const unsigned short* Be = WdT + ((size_t)e * DDIM + (size_t)bn * 256) * HDIM;
  const int tid = threadIdx.x;
  const int lane = tid & 63;
  const int wid = tid >> 6;
  const int wm = (wid & 1) * 128;
  const int wn = (wid >> 1) * 64;
  const int lr = lane & 15;
  const int lk = lane >> 4;

  f32x4 acc[8][4];
#pragma unroll
  for (int i = 0; i < 8; ++i)
#pragma unroll
    for (int j = 0; j < 4; ++j) acc[i][j] = f32x4{0.f, 0.f, 0.f, 0.f};

  auto stageA = [&](int t, int half) {
    stage_half(Ae + (size_t)(half * 128) * HDIM + t * 64, HDIM,
               (unsigned short*)smem[t & 1][0] + half * (128 * 64), tid);
  };
  auto stageB = [&](int t, int half) {
    stage_half(Be + (size_t)(half * 128) * HDIM + t * 64, HDIM,
               (unsigned short*)smem[t & 1][1] + half * (128 * 64), tid);
  };

  stageB(0, 0); stageB(0, 1); stageA(0, 0); stageA(0, 1);
  stageB(1, 0); stageB(1, 1); stageA(1, 0); stageA(1, 1);

  const int NT = HDIM / 64;   // 64
  for (int t = 0; t < NT; ++t) {
    const unsigned short* A = smem[t & 1][0];
    const unsigned short* B = smem[t & 1][1];
    if (t + 1 < NT) { WAIT_VM8(); } else { WAIT_VM0(); }
    SBAR(); SCHED0();
    bf16x8 a0[4][2], a1[4][2], b0[2][2], b1[2][2];
    // ---- ph1: read a0(8), b0(4); MFMA (m0,n0)
#pragma unroll
    for (int mi = 0; mi < 4; ++mi)
#pragma unroll
      for (int kh = 0; kh < 2; ++kh)
        a0[mi][kh] = read_frag(A, wm + mi * 16 + lr, kh * 4 + lk);
#pragma unroll
    for (int ni = 0; ni < 2; ++ni)
#pragma unroll
      for (int kh = 0; kh < 2; ++kh)
        b0[ni][kh] = read_frag(B, wn + ni * 16 + lr, kh * 4 + lk);
    __builtin_amdgcn_s_setprio(1);
#pragma unroll
    for (int kh = 0; kh < 2; ++kh)
#pragma unroll
      for (int mi = 0; mi < 4; ++mi)
#pragma unroll
        for (int ni = 0; ni < 2; ++ni)
          acc[mi][ni] = MFMA_BF16(a0[mi][kh], b0[ni][kh], acc[mi][ni]);
    __builtin_amdgcn_s_setprio(0);
    SBAR(); SCHED0();
    // ---- ph2: read b1(4); MFMA (m0,n1)
#pragma unroll
    for (int ni = 0; ni < 2; ++ni)
#pragma unroll
      for (int kh = 0; kh < 2; ++kh)
        b1[ni][kh] = read_frag(B, wn + 32 + ni * 16 + lr, kh * 4 + lk);
    __builtin_amdgcn_s_setprio(1);
#pragma unroll
    for (int kh = 0; kh < 2; ++kh)
#pragma unroll
      for (int mi = 0; mi < 4; ++mi)
#pragma unroll
        for (int ni = 0; ni < 2; ++ni)
          acc[mi][2 + ni] = MFMA_BF16(a0[mi][kh], b1[ni][kh], acc[mi][2 + ni]);
    __builtin_amdgcn_s_setprio(0);
    SBAR(); SCHED0();
    // ---- ph3: read a1(8); stage B0,B1(t+2); MFMA (m1,n0)
#pragma unroll
    for (int mi = 0; mi < 4; ++mi)
#pragma unroll
      for (int kh = 0; kh < 2; ++kh)
        a1[mi][kh] = read_frag(A, wm + 64 + mi * 16 + lr, kh * 4 + lk);
    if (t + 2 < NT) { stageB(t + 2, 0); stageB(t + 2, 1); }
    __builtin_amdgcn_s_setprio(1);
#pragma unroll
    for (int kh = 0; kh < 2; ++kh)
#pragma unroll
      for (int mi = 0; mi < 4; ++mi)
#pragma unroll
        for (int ni = 0; ni < 2; ++ni)
          acc[4 + mi][ni] = MFMA_BF16(a1[mi][kh], b0[ni][kh], acc[4 + mi][ni]);
    __builtin_amdgcn_s_setprio(0);
    SBAR(); SCHED0();
    // ---- ph4: stage A0,A1(t+2); MFMA (m1,n1)
    if (t + 2 < NT) { stageA(t + 2, 0); stageA(t + 2, 1); }
    __builtin_amdgcn_s_setprio(1);
#pragma unroll
    for (int kh = 0; kh < 2; ++kh)
#pragma unroll
      for (int mi = 0; mi < 4; ++mi)
#pragma unroll
        for (int ni = 0; ni < 2; ++ni)
          acc[4 + mi][2 + ni] = MFMA_BF16(a1[mi][kh], b1[ni][kh], acc[4 + mi][2 + ni]);
    __builtin_amdgcn_s_setprio(0);
  }

  float* Oe = Out + ((size_t)e * TTOK + bm * 256) * DDIM + (size_t)bn * 256;
#pragma unroll
  for (int mi = 0; mi < 8; ++mi) {
    int mrow = wm + ((mi < 4) ? mi * 16 : 64 + (mi - 4) * 16);
#pragma unroll
    for (int ni = 0; ni < 4; ++ni) {
      int col = wn + ((ni < 2) ? ni * 16 : 32 + (ni - 2) * 16) + lr;
#pragma unroll
      for (int r = 0; r < 4; ++r) {
        int row = mrow + lk * 4 + r;
        Oe[(size_t)row * DDIM + col] = acc[mi][ni][r];
      }
    }
  }
}

extern "C" void kernel_launch(void* const* d_in, const int* in_sizes, int n_in,
                              void* d_out, int out_size, void* d_ws, size_t ws_size,
                              hipStream_t stream) {
  const float* x = (const float*)d_in[0];
  const float* wug = (const float*)d_in[1];
  const float* wd = (const float*)d_in[2];
  float* out = (float*)d_out;

  unsigned short* xb   = (unsigned short*)d_ws;                    // 32768*2048
  unsigned short* wugb = xb   + (size_t)NTOK * DDIM;               // 8*8192*2048
  unsigned short* wdT  = wugb + (size_t)NEXP * 2 * HDIM * DDIM;    // 8*2048*4096
  unsigned short* hid  = wdT  + (size_t)NEXP * DDIM * HDIM;        // 8*4096*4096

  cvt_kernel<<<4096, 256, 0, stream>>>(x, xb, (long)NTOK * DDIM / 4);
  cvt_kernel<<<4096, 256, 0, stream>>>(wug, wugb, (long)NEXP * 2 * HDIM * DDIM / 4);
  transpose_wd<<<dim3(DDIM / 64, HDIM / 64, NEXP), 256, 0, stream>>>(wd, wdT);
  gemm1_swiglu<<<dim3(HDIM / 128, TTOK / 256, NEXP), 512, 0, stream>>>(xb, wugb, hid);
  gemm2_down<<<dim3(DDIM / 256, TTOK / 256, NEXP), 512, 0, stream>>>(hid, wdT, out);
}